// Round 2
// baseline (918.308 us; speedup 1.0000x reference)
//
#include <hip/hip_runtime.h>
#include <math.h>

#define NB 64
#define NN 4096
#define ND 256
#define NS 256
#define NK 8
#define NH 512
#define NROW (NB*NN)
#define NSLOT (NB*NK)
#define EPSA 1e-8f
#define NCG 16            // n-chunks per batch in attn (256 n each)

typedef unsigned short u16;
typedef unsigned int   u32;
typedef __bf16 bf16x8 __attribute__((ext_vector_type(8)));
typedef float  f32x4  __attribute__((ext_vector_type(4)));

__device__ __forceinline__ u16 f2bf(float f) {
  union { float f; u32 i; } v; v.f = f;
  u32 x = v.i;
  return (u16)((x + 0x7FFFu + ((x >> 16) & 1u)) >> 16);
}
__device__ __forceinline__ u32 pack2(float a, float b) {
  return (u32)f2bf(a) | ((u32)f2bf(b) << 16);
}

// ---------------- workspace layout (bytes) ----------------
// kpre: A-frag layout. tile = (global_n>>4)*8 + ks ; halfword offset in tile =
//       (n&15)*32 + ((d>>3)&3)*8 + (d&7)          [d = k-dim 0..255]
// vpre: B-frag layout, per batch b. tile = (d>>4)*128 + (nn>>5) ; offset =
//       (d&15)*32 + ((nn>>3)&3)*8 + (nn&7)        [d = v-dim 0..255]
#define OFF_XBF    0ULL            // 134217728
#define OFF_KPRE   134217728ULL    // 134217728
#define OFF_VPRE   268435456ULL    // 134217728
#define OFF_SLOTS  402653184ULL    // 524288
#define OFF_QBF    403177472ULL    // 262144
#define OFF_UPDP   403439616ULL    // 64*16*8*256 f32 = 8388608
#define OFF_SUMSP  411828224ULL    // 64*16*8 f32 = 32768
#define OFF_WC     411860992ULL    // 262144
#define OFF_WQT    412123136ULL    // 262144
#define OFF_WIHT   412385280ULL    // 786432
#define OFF_WHHT   413171712ULL    // 786432
#define OFF_W1T    413958144ULL    // 524288
#define OFF_W2T    414482432ULL    // 524288  (end ~396 MB)

// ---------------- K0: weight prep (proven) ----------------
__global__ __launch_bounds__(256) void prep_kernel(
    const float* __restrict__ Wq, const float* __restrict__ Wk, const float* __restrict__ Wv,
    const float* __restrict__ Wih, const float* __restrict__ Whh,
    const float* __restrict__ W1, const float* __restrict__ W2,
    u16* __restrict__ Wc, float* __restrict__ WqT, float* __restrict__ WihT,
    float* __restrict__ WhhT, float* __restrict__ W1T, float* __restrict__ W2T)
{
  int idx = blockIdx.x * 256 + threadIdx.x;   // 768*256
  if (idx < 512*256) {
    int j = idx >> 8, d = idx & 255;
    float w = (j < 256) ? Wk[idx] * 0.0625f : Wv[idx - 65536];
    Wc[idx] = f2bf(w);
    W1T[d*512 + j] = W1[idx];
  }
  if (idx < 256*256) {
    int j = idx >> 8, d = idx & 255;
    WqT[d*256 + j] = Wq[idx];
  }
  if (idx < 768*256) {
    int j = idx >> 8, d = idx & 255;
    WihT[d*768 + j] = Wih[idx];
    WhhT[d*768 + j] = Whh[idx];
  }
  if (idx < 256*512) {
    int j = idx >> 9, h = idx & 511;
    W2T[h*256 + j] = W2[idx];
  }
}

// ---------------- K1: slots init ----------------
__global__ __launch_bounds__(256) void slots_init_kernel(
    const float* __restrict__ noise, const float* __restrict__ mu,
    const float* __restrict__ lsig, float* __restrict__ slots)
{
  int idx = blockIdx.x * 256 + threadIdx.x;
  int s = idx & 255;
  slots[idx] = mu[s] + expf(lsig[s]) * noise[idx];
}

// ---------------- K2: LayerNorm(inputs) -> bf16 (r1 proven) ----------------
__global__ __launch_bounds__(256) void ln_cast_kernel(
    const float* __restrict__ x, const float* __restrict__ g, const float* __restrict__ bb,
    u16* __restrict__ out)
{
  int row = blockIdx.x * 4 + (threadIdx.x >> 6);
  int lane = threadIdx.x & 63;
  float4 xv = *(const float4*)(x + (size_t)row * 256 + lane * 4);
  float s  = xv.x + xv.y + xv.z + xv.w;
  float sq = xv.x*xv.x + xv.y*xv.y + xv.z*xv.z + xv.w*xv.w;
  #pragma unroll
  for (int m = 32; m >= 1; m >>= 1) { s += __shfl_xor(s, m, 64); sq += __shfl_xor(sq, m, 64); }
  float mean = s * (1.f/256.f);
  float rstd = rsqrtf(sq * (1.f/256.f) - mean*mean + 1e-5f);
  float4 gv = *(const float4*)(g + lane*4);
  float4 bv = *(const float4*)(bb + lane*4);
  ushort4 o;
  o.x = f2bf((xv.x - mean) * rstd * gv.x + bv.x);
  o.y = f2bf((xv.y - mean) * rstd * gv.y + bv.y);
  o.z = f2bf((xv.z - mean) * rstd * gv.z + bv.z);
  o.w = f2bf((xv.w - mean) * rstd * gv.w + bv.w);
  *(ushort4*)(out + (size_t)row * 256 + lane*4) = o;
}

// ---------------- K3: kv GEMM -> kpre / vpre frag layouts ----------------
// grid 8192 linear; bn = idx&3 (fastest -> A-tile L2/L3 reuse), bm = idx>>2.
// NEW: epilogue stages the 32KB output tile through LDS in two 16KB passes,
// flushing with coalesced dwordx4 stores (replaces 64 scattered 2B stores/thread).
__global__ __launch_bounds__(256) void gemm_kv_kernel(
    const u16* __restrict__ A, const u16* __restrict__ Bt,
    u16* __restrict__ kpre, u16* __restrict__ vpre)
{
  __shared__ u16 smem[8192];          // As = smem[0..4095], Bs = smem[4096..8191]
  const int tid = threadIdx.x;
  const int lane = tid & 63;
  const int wv = tid >> 6;
  const int bm = blockIdx.x >> 2;
  const int bn = blockIdx.x & 3;
  const int wm = (wv & 1) * 64;
  const int wn = (wv >> 1) * 64;

  f32x4 acc[4][4] = {};

  for (int k0 = 0; k0 < 256; k0 += 32) {
    #pragma unroll
    for (int r = 0; r < 2; ++r) {
      int off = ((r*4 + wv) << 10) + lane*16;   // byte offset into 8KB tile
      int row = off >> 6;
      int col = (off & 63) >> 1;
      const u16* ga = A  + (size_t)(bm*128 + row) * 256 + k0 + col;
      const u16* gb = Bt + (size_t)(bn*128 + row) * 256 + k0 + col;
      __builtin_amdgcn_global_load_lds(
        (const __attribute__((address_space(1))) u32*)ga,
        (__attribute__((address_space(3))) u32*)((char*)smem + off), 16, 0, 0);
      __builtin_amdgcn_global_load_lds(
        (const __attribute__((address_space(1))) u32*)gb,
        (__attribute__((address_space(3))) u32*)((char*)smem + 8192 + off), 16, 0, 0);
    }
    __syncthreads();
    bf16x8 af[4], bfr[4];
    #pragma unroll
    for (int t4 = 0; t4 < 4; ++t4) {
      af[t4]  = *(const bf16x8*)&smem[(wm + t4*16 + (lane & 15)) * 32 + (lane >> 4) * 8];
      bfr[t4] = *(const bf16x8*)&smem[4096 + (wn + t4*16 + (lane & 15)) * 32 + (lane >> 4) * 8];
    }
    #pragma unroll
    for (int mt = 0; mt < 4; ++mt)
      #pragma unroll
      for (int nt = 0; nt < 4; ++nt)
        acc[mt][nt] = __builtin_amdgcn_mfma_f32_16x16x32_bf16(af[mt], bfr[nt], acc[mt][nt], 0, 0, 0);
    __syncthreads();
  }
  const int cr = (lane >> 4) * 4;   // C/D: row = quad*4+reg, col = lane&15 (verified)
  const int cc = lane & 15;
  if (bn < 2) {
    // ---- k half -> kpre. Block owns 8 ntiles x (4KB contiguous: ks=bn*4..bn*4+3).
    // Pass p stages ntiles p*4..p*4+3 (written by waves with wm>>4 == p*4).
    #pragma unroll
    for (int p = 0; p < 2; ++p) {
      if ((wm >> 4) == p*4) {
        #pragma unroll
        for (int mt = 0; mt < 4; ++mt) {
          #pragma unroll
          for (int nt = 0; nt < 4; ++nt) {
            int dl = wn + nt*16 + cc;            // 0..127 within this block's d-half
            int ks_local = dl >> 5;              // 0..3
            int d = bn*128 + dl;
            int base_hw = mt*2048 + ks_local*512 + ((d>>3)&3)*8 + (d&7);
            #pragma unroll
            for (int r = 0; r < 4; ++r)
              smem[base_hw + (cr + r)*32] = f2bf(acc[mt][nt][r]);
          }
        }
      }
      __syncthreads();
      {
        int ntile_g = bm*8 + p*4 + wv;           // wave wv flushes LDS slot wv
        u16* gbase = kpre + ((size_t)ntile_g*8 + bn*4)*512;
        #pragma unroll
        for (int i = 0; i < 4; ++i) {
          ulonglong2 vdat = *(const ulonglong2*)&smem[wv*2048 + i*512 + lane*8];
          *(ulonglong2*)(gbase + i*512 + lane*8) = vdat;
        }
      }
      if (p == 0) __syncthreads();
    }
  } else {
    // ---- v half -> vpre. Block owns 8 dtiles x (4KB contiguous: 4 consecutive nn32).
    // Pass p stages dtiles p*4..p*4+3 (written by waves with wn>>4 == p*4).
    #pragma unroll
    for (int p = 0; p < 2; ++p) {
      if ((wn >> 4) == p*4) {
        #pragma unroll
        for (int nt = 0; nt < 4; ++nt) {
          int dv = (bn-2)*128 + wn + nt*16 + cc;
          #pragma unroll
          for (int mt = 0; mt < 4; ++mt) {
            int nl_base = wm + mt*16 + cr;       // + r -> 0..127 local n
            #pragma unroll
            for (int r = 0; r < 4; ++r) {
              int nl = nl_base + r;
              smem[nt*2048 + (nl>>5)*512 + (dv&15)*32 + ((nl>>3)&3)*8 + (nl&7)]
                = f2bf(acc[mt][nt][r]);
            }
          }
        }
      }
      __syncthreads();
      {
        int b = bm >> 5;
        int nnb5 = (bm & 31)*4;                  // nnbase>>5
        int dtile_g = (bn-2)*8 + p*4 + wv;       // wave wv flushes LDS slot wv
        u16* gbase = vpre + (size_t)b*1048576 + ((size_t)dtile_g*128 + nnb5)*512;
        #pragma unroll
        for (int i = 0; i < 4; ++i) {
          ulonglong2 vdat = *(const ulonglong2*)&smem[wv*2048 + i*512 + lane*8];
          *(ulonglong2*)(gbase + i*512 + lane*8) = vdat;
        }
      }
      if (p == 0) __syncthreads();
    }
  }
}

// ---------------- K4: q = LN(slots)@Wq^T -> bf16 (initial q only) ----------------
__global__ __launch_bounds__(256) void q_kernel(
    const float* __restrict__ slots, const float* __restrict__ gw, const float* __restrict__ bw,
    const float* __restrict__ WqT, u16* __restrict__ qbf)
{
  __shared__ float ln[2][256];
  int t = threadIdx.x, wv = t >> 6, lane = t & 63;
  int base = blockIdx.x * 2;
  if (wv < 2) {
    int row = base + wv;
    float4 xv = *(const float4*)(slots + (size_t)row*256 + lane*4);
    float s  = xv.x + xv.y + xv.z + xv.w;
    float sq = xv.x*xv.x + xv.y*xv.y + xv.z*xv.z + xv.w*xv.w;
    #pragma unroll
    for (int m = 32; m >= 1; m >>= 1) { s += __shfl_xor(s, m, 64); sq += __shfl_xor(sq, m, 64); }
    float mean = s * (1.f/256.f);
    float rstd = rsqrtf(sq * (1.f/256.f) - mean*mean + 1e-5f);
    float4 gv = *(const float4*)(gw + lane*4);
    float4 bv = *(const float4*)(bw + lane*4);
    ln[wv][lane*4+0] = (xv.x - mean)*rstd*gv.x + bv.x;
    ln[wv][lane*4+1] = (xv.y - mean)*rstd*gv.y + bv.y;
    ln[wv][lane*4+2] = (xv.z - mean)*rstd*gv.z + bv.z;
    ln[wv][lane*4+3] = (xv.w - mean)*rstd*gv.w + bv.w;
  }
  __syncthreads();
  float a0 = 0.f, a1 = 0.f;
  for (int d = 0; d < 256; ++d) {
    float w = WqT[d*256 + t];
    a0 += ln[0][d] * w;
    a1 += ln[1][d] * w;
  }
  qbf[(size_t)base*256 + t]     = f2bf(a0);
  qbf[(size_t)(base+1)*256 + t] = f2bf(a1);
}

// ---------------- K5: attn v6 — frag-native streaming, 1 barrier ----------------
// grid (64 b, 16 cg); 256 n per block. Only attnT (4.2KB) in LDS.
__global__ __launch_bounds__(256) void attn_kernel(
    const u16* __restrict__ kpre, const u16* __restrict__ vpre, const u16* __restrict__ qbf,
    float* __restrict__ updp, float* __restrict__ sums_p)
{
  __shared__ u16 attnT[8*264];    // [slot][n], pad 264 (bank-spread)
  __shared__ float sums_w[4][8];
  const int b = blockIdx.x, cg = blockIdx.y;
  const int t = threadIdx.x, w = t >> 6, lane = t & 63;
  const int L15 = lane & 15, q4 = lane >> 4;
  const int slot = L15 & 7;

  // q B-frags
  bf16x8 qf[8];
  {
    const u16* qp = qbf + ((size_t)b*8 + slot)*256;
    #pragma unroll
    for (int ks = 0; ks < 8; ++ks)
      qf[ks] = *(const bf16x8*)(qp + ks*32 + q4*8);
  }

  // ---- logits + softmax: wave w covers n = w*64 .. w*64+63 (4 ntiles of 16) ----
  const u16* kbase = kpre + (size_t)(b*256 + cg*16)*8*512 + L15*32 + q4*8;
  float tot = 0.f;
  #pragma unroll
  for (int i = 0; i < 4; ++i) {
    f32x4 lg = {};
    const u16* ktile = kbase + (size_t)(w*4 + i)*8*512;
    #pragma unroll
    for (int ks = 0; ks < 8; ++ks) {
      bf16x8 af = *(const bf16x8*)(ktile + ks*512);
      lg = __builtin_amdgcn_mfma_f32_16x16x32_bf16(af, qf[ks], lg, 0, 0, 0);
    }
    float av[4];
    #pragma unroll
    for (int r = 0; r < 4; ++r) {
      float val = lg[r];
      float mx = val;
      mx = fmaxf(mx, __shfl_xor(mx, 1, 64));
      mx = fmaxf(mx, __shfl_xor(mx, 2, 64));
      mx = fmaxf(mx, __shfl_xor(mx, 4, 64));
      float e = expf(val - mx);
      float se = e;
      se += __shfl_xor(se, 1, 64);
      se += __shfl_xor(se, 2, 64);
      se += __shfl_xor(se, 4, 64);
      av[r] = e / se + EPSA;
      tot += av[r];
    }
    if (L15 < 8) {
      u32* p = (u32*)&attnT[slot*264 + (w*4 + i)*16 + q4*4];
      p[0] = pack2(av[0], av[1]);
      p[1] = pack2(av[2], av[3]);
    }
  }
  tot += __shfl_xor(tot, 16, 64);
  tot += __shfl_xor(tot, 32, 64);
  if (q4 == 0 && L15 < 8) sums_w[w][L15] = tot;
  __syncthreads();   // the ONE barrier

  // ---- PV: A = attnT (LDS), B = vpre frags (global, coalesced) ----
  f32x4 accp[4] = {};
  const u16* vbase = vpre + (size_t)b*1048576 + L15*32 + q4*8;
  #pragma unroll
  for (int ks2 = 0; ks2 < 8; ++ks2) {
    bf16x8 pa = *(const bf16x8*)&attnT[slot*264 + ks2*32 + q4*8];
    #pragma unroll
    for (int dt = 0; dt < 4; ++dt) {
      int dtile = w*4 + dt;
      bf16x8 vb = *(const bf16x8*)(vbase + (size_t)(dtile*128 + cg*8 + ks2)*512);
      accp[dt] = __builtin_amdgcn_mfma_f32_16x16x32_bf16(pa, vb, accp[dt], 0, 0, 0);
    }
  }
  if (q4 < 2) {
    float* up = updp + ((size_t)(b*NCG + cg))*2048;
    #pragma unroll
    for (int dt = 0; dt < 4; ++dt) {
      int d = (w*4 + dt)*16 + L15;
      #pragma unroll
      for (int r = 0; r < 4; ++r)
        up[(q4*4 + r)*256 + d] = accp[dt][r];
    }
  }
  if (t < 8)
    sums_p[(b*NCG + cg)*8 + t] = sums_w[0][t] + sums_w[1][t] + sums_w[2][t] + sums_w[3][t];
}

// ---------------- K6: reduce + GRU + MLP + next-iter q (fused) ----------------
// NEW: 256 blocks x 512 threads; wave-group g = tid>>8 owns one slot-row.
// Doubles occupancy (1 -> 2 waves/SIMD); both halves read the same weight
// addresses -> L1-served.
__global__ __launch_bounds__(512) void grumlp_kernel(
    const float* __restrict__ updp, const float* __restrict__ sums_p,
    const float* __restrict__ WihT, const float* __restrict__ WhhT,
    const float* __restrict__ bih, const float* __restrict__ bhh,
    const float* __restrict__ gm, const float* __restrict__ bm,
    const float* __restrict__ W1T, const float* __restrict__ b1,
    const float* __restrict__ W2T, const float* __restrict__ b2,
    const float* __restrict__ gq, const float* __restrict__ bq,
    const float* __restrict__ WqT,
    float* __restrict__ slots, u16* __restrict__ qbf, int do_mlp)
{
  __shared__ float xs[2][256], hs[2][256];
  __shared__ float ln[2][256];
  __shared__ float hb[2][512];
  int tt = threadIdx.x;          // 0..511
  int g = tt >> 8;               // row half
  int t = tt & 255;              // output column
  int w = tt >> 6, lane = tt & 63;
  int base = blockIdx.x * 2;
  {
    int row = base + g;
    int b = row >> 3, s = row & 7;
    float u = 0.f, sm = 0.f;
    #pragma unroll
    for (int c = 0; c < NCG; ++c) {
      u  += updp[((size_t)(b*NCG + c)*8 + s)*256 + t];
      sm += sums_p[(b*NCG + c)*8 + s];
    }
    xs[g][t] = u / sm;
    hs[g][t] = slots[(size_t)row*256 + t];
  }
  __syncthreads();
  float ra = 0.f, za = 0.f, ia = 0.f, ha = 0.f;
  for (int d = 0; d < 256; ++d) {
    float wir = WihT[d*768 + t], wiz = WihT[d*768 + 256 + t], win = WihT[d*768 + 512 + t];
    float whr = WhhT[d*768 + t], whz = WhhT[d*768 + 256 + t], whn = WhhT[d*768 + 512 + t];
    float xx = xs[g][d], hh = hs[g][d];
    ra += xx*wir + hh*whr;
    za += xx*wiz + hh*whz;
    ia += xx*win;
    ha += hh*whn;
  }
  float bir = bih[t], biz = bih[256+t], bin = bih[512+t];
  float bhr = bhh[t], bhz = bhh[256+t], bhn = bhh[512+t];
  float nv;
  {
    float r  = 1.f/(1.f + expf(-(ra + bir + bhr)));
    float z  = 1.f/(1.f + expf(-(za + biz + bhz)));
    float nn = tanhf(ia + bin + r*(ha + bhn));
    nv = (1.f - z)*nn + z*hs[g][t];
  }
  if (!do_mlp) {
    slots[(size_t)(base+g)*256 + t] = nv;
    return;
  }
  xs[g][t] = nv;
  __syncthreads();
  // LN (g_mlp) — waves 0,1 own rows 0,1
  if (w < 2) {
    float4 xv = *(const float4*)&xs[w][lane*4];
    float s  = xv.x + xv.y + xv.z + xv.w;
    float sq = xv.x*xv.x + xv.y*xv.y + xv.z*xv.z + xv.w*xv.w;
    #pragma unroll
    for (int m = 32; m >= 1; m >>= 1) { s += __shfl_xor(s, m, 64); sq += __shfl_xor(sq, m, 64); }
    float mean = s * (1.f/256.f);
    float rstd = rsqrtf(sq * (1.f/256.f) - mean*mean + 1e-5f);
    float4 gv = *(const float4*)(gm + lane*4);
    float4 bv = *(const float4*)(bm + lane*4);
    ln[w][lane*4+0] = (xv.x - mean)*rstd*gv.x + bv.x;
    ln[w][lane*4+1] = (xv.y - mean)*rstd*gv.y + bv.y;
    ln[w][lane*4+2] = (xv.z - mean)*rstd*gv.z + bv.z;
    ln[w][lane*4+3] = (xv.w - mean)*rstd*gv.w + bv.w;
  }
  __syncthreads();
  float h0 = 0.f, h1 = 0.f;
  for (int d = 0; d < 256; ++d) {
    float w0 = W1T[d*512 + t], w1 = W1T[d*512 + 256 + t];
    float l = ln[g][d];
    h0 += l*w0; h1 += l*w1;
  }
  hb[g][t]       = fmaxf(h0 + b1[t], 0.f);
  hb[g][256 + t] = fmaxf(h1 + b1[256 + t], 0.f);
  __syncthreads();
  float o = 0.f;
  for (int hh = 0; hh < 512; ++hh) {
    float ww = W2T[hh*256 + t];
    o += hb[g][hh] * ww;
  }
  float snew = xs[g][t] + o + b2[t];
  slots[(size_t)(base+g)*256 + t] = snew;
  __syncthreads();               // xs write below must not race LN readers above
  xs[g][t] = snew;
  __syncthreads();
  // LN (g_sl) for next-iter q — waves 0,1 own rows 0,1
  if (w < 2) {
    float4 xv = *(const float4*)&xs[w][lane*4];
    float s  = xv.x + xv.y + xv.z + xv.w;
    float sq = xv.x*xv.x + xv.y*xv.y + xv.z*xv.z + xv.w*xv.w;
    #pragma unroll
    for (int m = 32; m >= 1; m >>= 1) { s += __shfl_xor(s, m, 64); sq += __shfl_xor(sq, m, 64); }
    float mean = s * (1.f/256.f);
    float rstd = rsqrtf(sq * (1.f/256.f) - mean*mean + 1e-5f);
    float4 gv = *(const float4*)(gq + lane*4);
    float4 bv = *(const float4*)(bq + lane*4);
    ln[w][lane*4+0] = (xv.x - mean)*rstd*gv.x + bv.x;
    ln[w][lane*4+1] = (xv.y - mean)*rstd*gv.y + bv.y;
    ln[w][lane*4+2] = (xv.z - mean)*rstd*gv.z + bv.z;
    ln[w][lane*4+3] = (xv.w - mean)*rstd*gv.w + bv.w;
  }
  __syncthreads();
  float a0 = 0.f;
  for (int d = 0; d < 256; ++d)
    a0 += ln[g][d] * WqT[d*256 + t];
  qbf[(size_t)(base+g)*256 + t] = f2bf(a0);
}

// ---------------- host ----------------
extern "C" void kernel_launch(void* const* d_in, const int* in_sizes, int n_in,
                              void* d_out, int out_size, void* d_ws, size_t ws_size,
                              hipStream_t stream)
{
  (void)in_sizes; (void)n_in; (void)out_size; (void)ws_size;
  const float* inputs = (const float*)d_in[0];
  const float* noise  = (const float*)d_in[1];
  const float* mu     = (const float*)d_in[2];
  const float* lsig   = (const float*)d_in[3];
  const float* g_in   = (const float*)d_in[4];
  const float* b_in   = (const float*)d_in[5];
  const float* g_sl   = (const float*)d_in[6];
  const float* b_sl   = (const float*)d_in[7];
  const float* g_mlp  = (const float*)d_in[8];
  const float* b_mlp  = (const float*)d_in[9];
  const float* Wq     = (const float*)d_in[10];
  const float* Wk     = (const float*)d_in[11];
  const float* Wv     = (const float*)d_in[12];
  const float* Wih    = (const float*)d_in[13];
  const float* Whh    = (const float*)d_in[14];
  const float* bih    = (const float*)d_in[15];
  const float* bhh    = (const float*)d_in[16];
  const float* W1     = (const float*)d_in[17];
  const float* b1     = (const float*)d_in[18];
  const float* W2     = (const float*)d_in[19];
  const float* b2     = (const float*)d_in[20];

  char* ws = (char*)d_ws;
  u16*   x_bf   = (u16*)  (ws + OFF_XBF);
  u16*   kpre   = (u16*)  (ws + OFF_KPRE);
  u16*   vpre   = (u16*)  (ws + OFF_VPRE);
  float* slots  = (float*)(ws + OFF_SLOTS);
  u16*   qb     = (u16*)  (ws + OFF_QBF);
  float* updp   = (float*)(ws + OFF_UPDP);
  float* sums_p = (float*)(ws + OFF_SUMSP);
  u16*   Wc     = (u16*)  (ws + OFF_WC);
  float* WqT    = (float*)(ws + OFF_WQT);
  float* WihT   = (float*)(ws + OFF_WIHT);
  float* WhhT   = (float*)(ws + OFF_WHHT);
  float* W1T    = (float*)(ws + OFF_W1T);
  float* W2T    = (float*)(ws + OFF_W2T);

  prep_kernel<<<768, 256, 0, stream>>>(Wq, Wk, Wv, Wih, Whh, W1, W2,
                                       Wc, WqT, WihT, WhhT, W1T, W2T);
  slots_init_kernel<<<512, 256, 0, stream>>>(noise, mu, lsig, slots);
  ln_cast_kernel<<<NROW/4, 256, 0, stream>>>(inputs, g_in, b_in, x_bf);
  gemm_kv_kernel<<<8192, 256, 0, stream>>>(x_bf, Wc, kpre, vpre);
  q_kernel<<<NSLOT/2, 256, 0, stream>>>(slots, g_sl, b_sl, WqT, qb);

  for (int it = 0; it < 3; ++it) {
    attn_kernel<<<dim3(NB, NCG), 256, 0, stream>>>(kpre, vpre, qb, updp, sums_p);
    grumlp_kernel<<<NSLOT/2, 512, 0, stream>>>(updp, sums_p, WihT, WhhT, bih, bhh,
                                               g_mlp, b_mlp, W1T, b1, W2T, b2,
                                               g_sl, b_sl, WqT,
                                               slots, qb, (it < 2) ? 1 : 0);
  }
  hipMemcpyAsync(d_out, slots, (size_t)NSLOT*NS*sizeof(float),
                 hipMemcpyDeviceToDevice, stream);
}